// Round 1
// baseline (812.326 us; speedup 1.0000x reference)
//
#include <hip/hip_runtime.h>
#include <hip/hip_bf16.h>
#include <math.h>

#define T_TOK 4096
#define HID   4096
#define NHQ   32
#define NKVH  8
#define HDIM  128
#define SEQ   1024
#define NBATCH 4

typedef __attribute__((ext_vector_type(8))) short bf16x8;
typedef __attribute__((ext_vector_type(4))) float f32x4;
typedef __attribute__((ext_vector_type(16))) float f32x16;

__device__ __forceinline__ unsigned short f2bf(float f) {
  union { float f; unsigned int u; } x; x.f = f;
  unsigned int r = x.u + 0x7FFFu + ((x.u >> 16) & 1u);
  return (unsigned short)(r >> 16);
}

// async global->LDS, 16B per lane. LDS dest must be wave-uniform base; HW adds lane*16.
#define GLOAD_LDS16(gp, lp)                                                        \
  __builtin_amdgcn_global_load_lds(                                                \
      (__attribute__((address_space(1))) void*)(unsigned long long)(const void*)(gp), \
      (__attribute__((address_space(3))) void*)(unsigned long long)(const void*)(lp), \
      16, 0, 0)

// ---------------- single fused cast fp32 -> bf16 for all 5 tensors -------------
__global__ __launch_bounds__(256) void cast_all_k(const float* __restrict__ x,
                                                  const float* __restrict__ wq,
                                                  const float* __restrict__ wk,
                                                  const float* __restrict__ wv,
                                                  const float* __restrict__ wo,
                                                  unsigned short* __restrict__ xb,
                                                  unsigned short* __restrict__ wqkv,
                                                  unsigned short* __restrict__ wob) {
  int i = blockIdx.x * 256 + threadIdx.x;  // float4 index, total 14680064
  const float* src; unsigned short* dst; int off;
  if (i < 4194304)       { src = x;  dst = xb;   off = i; }
  else if (i < 8388608)  { src = wq; dst = wqkv; off = i - 4194304; }
  else if (i < 9437184)  { src = wk; dst = wqkv + 16777216; off = i - 8388608; }
  else if (i < 10485760) { src = wv; dst = wqkv + 20971520; off = i - 9437184; }
  else                   { src = wo; dst = wob;  off = i - 10485760; }
  float4 f = ((const float4*)src)[off];
  ushort4 o;
  o.x = f2bf(f.x); o.y = f2bf(f.y); o.z = f2bf(f.z); o.w = f2bf(f.w);
  ((ushort4*)dst)[off] = o;
}

// ---------------- GEMM: C[M,N] = A[M,K] @ B[N,K]^T (bf16 in) ------------------
// 256x256 tile, BK=32, 8 waves (512 thr), 3-stage LDS ring, counted vmcnt(4),
// per-phase {ds_read || global_load_lds -> s_barrier -> setprio+MFMA}.
// Wave w: rows (w>>2)*128 (4x 32-row tiles), cols cb=(w&3): (w&3&1)*32+(w>>1&1... see cbl)
// owning column blocks {cbl, cbl+64} inside one 128-wide head window so the
// RoPE rotate-half partner (d, d+64) lives in the same lane at acc j=0/j=1.
// LDS: packed 2 logical rows per 128B row; chunk XOR (c ^ (row64&3)) ->
// conflict-free ds_read_b128 (2 lanes/16B-slot per quarter-wave).
template<bool FUSED>
__global__ __launch_bounds__(512, 2) void gemm8(const unsigned short* __restrict__ A,
                                                const unsigned short* __restrict__ B,
                                                float* __restrict__ C,
                                                const int* __restrict__ pos,
                                                unsigned short* __restrict__ qr,
                                                unsigned short* __restrict__ kr,
                                                unsigned short* __restrict__ vbuf,
                                                int N, int K) {
  __shared__ unsigned short As3[3][8192];  // 48 KB: 3 x (128 row64 x 64 shorts)
  __shared__ unsigned short Bs3[3][8192];  // 48 KB
  const int tid  = threadIdx.x;
  const int lane = tid & 63;
  const int wave = tid >> 6;
  const int half = lane >> 5;       // 0/1
  const int r31  = lane & 31;
  const int wml  = (wave >> 2) * 128;                       // M offset in tile
  const int wn   = wave & 3;
  const int cbl  = (wn & 1) * 32 + (wn >> 1) * 128;         // N offset in tile

  // XCD-aware swizzle on linearized wg id (nwg % 8 == 0 for both launches)
  const int gx = gridDim.x;
  const int nwg = gx * gridDim.y;
  const int orig = blockIdx.y * gx + blockIdx.x;
  const int swz = (orig & 7) * (nwg >> 3) + (orig >> 3);
  const long rowBase = (long)(swz / gx) * 256;
  const long colBase = (long)(swz % gx) * 256;

  // --- staging source mapping (fixed per thread; inverse of read swizzle) ---
  // issue covers one 128-row half: thread t -> LDS 16B-unit u=t:
  //   row64 = h*64 + (t>>3), slot j = t&7  =>  logical row r = 2*row64 + (j>>2),
  //   logical chunk c = (j&3) ^ (row64&3)   ((h*64)&3 == 0)
  const int sr64 = tid >> 3;
  const int sj   = tid & 7;
  const int scg  = ((sj & 3) ^ (sr64 & 3)) * 8;
  const long srow = (long)(sr64 * 2 + (sj >> 2));
  const unsigned short* srcA0 = A + (rowBase + srow) * (long)K + scg;
  const unsigned short* srcA1 = srcA0 + 128 * (long)K;
  const unsigned short* srcB0 = B + (colBase + srow) * (long)K + scg;
  const unsigned short* srcB1 = srcB0 + 128 * (long)K;
  const int dH0 = (wave * 8) * 64;        // LDS dest (shorts), wave-uniform
  const int dH1 = (64 + wave * 8) * 64;

  f32x16 acc[4][2] = {};
  const int nt = K >> 5;   // K-tiles of 32

  // prologue: stage tiles 0 and 1 (buffers 0,1)
  GLOAD_LDS16(srcA0,      &As3[0][dH0]);
  GLOAD_LDS16(srcA1,      &As3[0][dH1]);
  GLOAD_LDS16(srcB0,      &Bs3[0][dH0]);
  GLOAD_LDS16(srcB1,      &Bs3[0][dH1]);
  GLOAD_LDS16(srcA0 + 32, &As3[1][dH0]);
  GLOAD_LDS16(srcA1 + 32, &As3[1][dH1]);
  GLOAD_LDS16(srcB0 + 32, &Bs3[1][dH0]);
  GLOAD_LDS16(srcB1 + 32, &Bs3[1][dH1]);
  asm volatile("s_waitcnt vmcnt(4)" ::: "memory");  // tile 0 landed, tile 1 in flight
  __builtin_amdgcn_s_barrier();

  int q = 0, qs = 2;
  for (int t = 0; t < nt; ++t) {
    if (t) {
      // tile t's 4 loads (issued during t-2 / prologue) must retire; tile t+1's
      // 4 (issued during t-1) may stay in flight.
      if (t + 1 < nt) asm volatile("s_waitcnt vmcnt(4)" ::: "memory");
      else            asm volatile("s_waitcnt vmcnt(0)" ::: "memory");
      __builtin_amdgcn_s_barrier();
    }
    const unsigned short* Aq = &As3[q][0];
    const unsigned short* Bq = &Bs3[q][0];
    const bool doStage = (t + 2) < nt;
    const int koff = (t + 2) * 32;

    bf16x8 af[4], bfr[2];
    // ---------------- phase kk=0 ----------------
#pragma unroll
    for (int i = 0; i < 4; ++i) {
      int r = wml + i * 32 + r31;
      int r64 = r >> 1;
      af[i] = *(const bf16x8*)(Aq + r64 * 64 + (r & 1) * 32 + ((half ^ (r64 & 3)) * 8));
    }
#pragma unroll
    for (int j = 0; j < 2; ++j) {
      int r = cbl + j * 64 + r31;
      int r64 = r >> 1;
      bfr[j] = *(const bf16x8*)(Bq + r64 * 64 + (r & 1) * 32 + ((half ^ (r64 & 3)) * 8));
    }
    if (doStage) {  // A-halves of tile t+2 into buffer freed at top-of-tile barrier
      GLOAD_LDS16(srcA0 + koff, &As3[qs][dH0]);
      GLOAD_LDS16(srcA1 + koff, &As3[qs][dH1]);
    }
    __builtin_amdgcn_s_barrier();
    __builtin_amdgcn_s_setprio(1);
#pragma unroll
    for (int i = 0; i < 4; ++i)
#pragma unroll
      for (int j = 0; j < 2; ++j)
        acc[i][j] = __builtin_amdgcn_mfma_f32_32x32x16_bf16(af[i], bfr[j], acc[i][j], 0, 0, 0);
    __builtin_amdgcn_s_setprio(0);

    // ---------------- phase kk=1 ----------------
#pragma unroll
    for (int i = 0; i < 4; ++i) {
      int r = wml + i * 32 + r31;
      int r64 = r >> 1;
      af[i] = *(const bf16x8*)(Aq + r64 * 64 + (r & 1) * 32 + (((2 + half) ^ (r64 & 3)) * 8));
    }
#pragma unroll
    for (int j = 0; j < 2; ++j) {
      int r = cbl + j * 64 + r31;
      int r64 = r >> 1;
      bfr[j] = *(const bf16x8*)(Bq + r64 * 64 + (r & 1) * 32 + (((2 + half) ^ (r64 & 3)) * 8));
    }
    if (doStage) {  // B-halves of tile t+2
      GLOAD_LDS16(srcB0 + koff, &Bs3[qs][dH0]);
      GLOAD_LDS16(srcB1 + koff, &Bs3[qs][dH1]);
    }
    __builtin_amdgcn_s_barrier();
    __builtin_amdgcn_s_setprio(1);
#pragma unroll
    for (int i = 0; i < 4; ++i)
#pragma unroll
      for (int j = 0; j < 2; ++j)
        acc[i][j] = __builtin_amdgcn_mfma_f32_32x32x16_bf16(af[i], bfr[j], acc[i][j], 0, 0, 0);
    __builtin_amdgcn_s_setprio(0);

    q  = (q  == 2) ? 0 : q + 1;
    qs = (qs == 2) ? 0 : qs + 1;
  }

  if (!FUSED) {
#pragma unroll
    for (int i = 0; i < 4; ++i)
#pragma unroll
      for (int j = 0; j < 2; ++j) {
        long c = colBase + cbl + j * 64 + r31;
#pragma unroll
        for (int reg = 0; reg < 16; ++reg) {
          long row = rowBase + wml + i * 32 + 4 * half + (reg & 3) + 8 * (reg >> 2);
          C[row * N + c] = acc[i][j][reg];
        }
      }
    return;
  }

  // ---- fused epilogue: RoPE (q/k) or plain (v), bf16 scatter ----
  const int n0 = (int)colBase + (cbl & 128);  // 128-wide head window base
  unsigned short* dst;
  int rstride, colofs;
  bool dorope;
  if (n0 < 4096)       { dst = qr;   rstride = NHQ * HDIM;  colofs = n0;        dorope = true; }
  else if (n0 < 5120)  { dst = kr;   rstride = NKVH * HDIM; colofs = n0 - 4096; dorope = true; }
  else                 { dst = vbuf; rstride = NKVH * HDIM; colofs = n0 - 5120; dorope = false; }
  const float c0 = -13.287712379549449f / 64.0f;  // -log2(10000)/64
  const int d = (cbl & 127) + r31;                // 0..63, fixed per lane
  const float f1 = exp2f(c0 * (float)(d >> 1));
  const float f2 = exp2f(c0 * (float)((d >> 1) + 32));
#pragma unroll
  for (int i = 0; i < 4; ++i) {
#pragma unroll
    for (int reg = 0; reg < 16; ++reg) {
      int grow = (int)rowBase + wml + i * 32 + 4 * half + (reg & 3) + 8 * (reg >> 2);
      unsigned short* drow = dst + (long)grow * rstride + colofs;
      float lo = acc[i][0][reg], hi = acc[i][1][reg];
      if (dorope) {
        int p = pos[grow];
        p = p < 0 ? 0 : (p > SEQ - 1 ? SEQ - 1 : p);
        float pf = (float)p;
        float s1, cc1, s2, cc2;
        __sincosf(pf * f1, &s1, &cc1);
        __sincosf(pf * f2, &s2, &cc2);
        drow[d]      = f2bf(lo * cc1 - hi * s1);
        drow[d + 64] = f2bf(hi * cc2 + lo * s2);
      } else {
        drow[d]      = f2bf(lo);
        drow[d + 64] = f2bf(hi);
      }
    }
  }
}

// ---------------- Flash attention (causal, GQA), bf16 MFMA ----------------
#define ATT_SCALE_L2 0.12754227022f  // (1/sqrt(128)) * log2(e)
__global__ __launch_bounds__(256) void attn_k(const unsigned short* __restrict__ Qp,
                                              const unsigned short* __restrict__ Kp,
                                              const unsigned short* __restrict__ Vp,
                                              unsigned short* __restrict__ Op) {
  const int pr = blockIdx.x, h = blockIdx.y, b = blockIdx.z;
  const int kvh = h >> 2;
  const int tid = threadIdx.x, wave = tid >> 6, lane = tid & 63;
  const int m16 = lane & 15, quad = lane >> 4;

  __shared__ unsigned short Ks[64][128];   // [key][d], 16 chunks/row, 3-bit xor swizzle
  __shared__ unsigned short Vt[128][64];   // [d][key], 8 chunks/row, additive rotation
  __shared__ unsigned short Ps[4][32][64]; // per-wave P, additive rotation

  for (int pass = 0; pass < 2; ++pass) {
    const int qt = pass ? pr : (7 - pr);
    const int qbase = qt * 128;
    const int wq_lo = qbase + wave * 32;

    bf16x8 qa[2][4];
#pragma unroll
    for (int i = 0; i < 2; ++i) {
      const unsigned short* qrow =
          Qp + (long)(b * SEQ + wq_lo + i * 16 + m16) * (NHQ * HDIM) + h * HDIM;
#pragma unroll
      for (int kk = 0; kk < 4; ++kk)
        qa[i][kk] = *(const bf16x8*)(qrow + kk * 32 + quad * 8);
    }

    f32x4 o[2][8] = {};
    float mrow[2][4], lrow[2][4];
#pragma unroll
    for (int i = 0; i < 2; ++i)
#pragma unroll
      for (int r = 0; r < 4; ++r) { mrow[i][r] = -1e30f; lrow[i][r] = 0.f; }

    const int nkt = qt * 2 + 2;
    for (int kt = 0; kt < nkt; ++kt) {
      __syncthreads();
      const unsigned short* Kbase =
          Kp + (long)(b * SEQ + kt * 64) * (NKVH * HDIM) + kvh * HDIM;
      const unsigned short* Vbase =
          Vp + (long)(b * SEQ + kt * 64) * (NKVH * HDIM) + kvh * HDIM;
#pragma unroll
      for (int it = 0; it < 4; ++it) {
        int c = it * 256 + tid;
        int row = c >> 4, psg = c & 15;
        int sg = (psg & 8) | ((psg & 7) ^ (row & 7));
        GLOAD_LDS16(Kbase + row * (NKVH * HDIM) + sg * 8,
                    ((unsigned short*)Ks) + (it * 256 + wave * 64) * 8);
      }
#pragma unroll
      for (int it = 0; it < 4; ++it) {
        int seg = it * 4 + wave;  // wave-uniform
        uint4 dv = *(const uint4*)(Vbase + lane * (NKVH * HDIM) + seg * 8);
        const unsigned short* pv = (const unsigned short*)&dv;
#pragma unroll
        for (int e = 0; e < 8; ++e) {
          int d = seg * 8 + e;
          Vt[d][((((lane >> 3) + d) & 7) * 8) + (lane & 7)] = pv[e];
        }
      }
      __syncthreads();

      const bool active = (kt * 64) <= (wq_lo + 31);
      if (active) {
        f32x4 s4[2][4] = {};
#pragma unroll
        for (int kk = 0; kk < 4; ++kk) {
          bf16x8 kbf[4];
#pragma unroll
          for (int j = 0; j < 4; ++j) {
            int row = j * 16 + m16;
            int cl = kk * 4 + quad;
            int ps = (cl & 8) | ((cl & 7) ^ (row & 7));
            kbf[j] = *(const bf16x8*)(&Ks[row][ps * 8]);
          }
#pragma unroll
          for (int i = 0; i < 2; ++i)
#pragma unroll
            for (int j = 0; j < 4; ++j)
              s4[i][j] = __builtin_amdgcn_mfma_f32_16x16x32_bf16(qa[i][kk], kbf[j], s4[i][j], 0, 0, 0);
        }
        const bool full = (kt * 64 + 63) <= wq_lo;
#pragma unroll
        for (int i = 0; i < 2; ++i) {
#pragma unroll
          for (int r = 0; r < 4; ++r) {
            const int qrow = i * 16 + quad * 4 + r;
            const int qi = qbase + wave * 32 + qrow;
            float v[4];
#pragma unroll
            for (int j = 0; j < 4; ++j) {
              v[j] = s4[i][j][r] * ATT_SCALE_L2;
              if (!full && (kt * 64 + j * 16 + m16 > qi)) v[j] = -1e30f;
            }
            float mx = fmaxf(fmaxf(v[0], v[1]), fmaxf(v[2], v[3]));
            mx = fmaxf(mx, __shfl_xor(mx, 1));
            mx = fmaxf(mx, __shfl_xor(mx, 2));
            mx = fmaxf(mx, __shfl_xor(mx, 4));
            mx = fmaxf(mx, __shfl_xor(mx, 8));
            float mold = mrow[i][r];
            float mnew = fmaxf(mold, mx);
            float alpha = exp2f(mold - mnew);
            float rs = 0.f;
#pragma unroll
            for (int j = 0; j < 4; ++j) {
              float pj = exp2f(v[j] - mnew);
              rs += pj;
              int col = j * 16 + m16;
              Ps[wave][qrow][((((col >> 3) + qrow) & 7) * 8) + (col & 7)] = f2bf(pj);
            }
            rs += __shfl_xor(rs, 1); rs += __shfl_xor(rs, 2);
            rs += __shfl_xor(rs, 4); rs += __shfl_xor(rs, 8);
            lrow[i][r] = lrow[i][r] * alpha + rs;
            mrow[i][r] = mnew;
#pragma unroll
            for (int n = 0; n < 8; ++n) o[i][n][r] *= alpha;
          }
        }
#pragma unroll
        for (int kk = 0; kk < 2; ++kk) {
          bf16x8 pa[2], vb[8];
#pragma unroll
          for (int i = 0; i < 2; ++i) {
            int row = i * 16 + m16;
            pa[i] = *(const bf16x8*)(&Ps[wave][row][(((kk * 4 + quad) + row) & 7) * 8]);
          }
#pragma unroll
          for (int n = 0; n < 8; ++n) {
            int row = n * 16 + m16;
            vb[n] = *(const bf16x8*)(&Vt[row][(((kk * 4 + quad) + row) & 7) * 8]);
          }
#pragma unroll
          for (int i = 0; i < 2; ++i)
#pragma unroll
            for (int n = 0; n < 8; ++n)
              o[i][n] = __builtin_amdgcn_mfma_f32_16x16x32_bf16(pa[i], vb[n], o[i][n], 0, 0, 0);
        }
      }
    }
#pragma unroll
    for (int i = 0; i < 2; ++i) {
#pragma unroll
      for (int r = 0; r < 4; ++r) {
        float inv = 1.0f / lrow[i][r];
        unsigned short* orow =
            Op + (long)(b * SEQ + wq_lo + i * 16 + quad * 4 + r) * (NHQ * HDIM) + h * HDIM;
#pragma unroll
        for (int n = 0; n < 8; ++n)
          orow[n * 16 + m16] = f2bf(o[i][n][r] * inv);
      }
    }
  }
}

// ---------------- launch ----------------
extern "C" void kernel_launch(void* const* d_in, const int* in_sizes, int n_in,
                              void* d_out, int out_size, void* d_ws, size_t ws_size,
                              hipStream_t stream) {
  (void)in_sizes; (void)n_in; (void)out_size; (void)ws_size;
  const float* x  = (const float*)d_in[0];
  const int* pos  = (const int*)d_in[1];
  const float* wq = (const float*)d_in[3];
  const float* wk = (const float*)d_in[4];
  const float* wv = (const float*)d_in[5];
  const float* wo = (const float*)d_in[6];
  float* out = (float*)d_out;

  char* ws = (char*)d_ws;
  unsigned short* xb    = (unsigned short*)(ws);                   // 32MB bf16 x
  unsigned short* wqkv  = (unsigned short*)(ws + (32ll << 20));    // 48MB bf16 [wq;wk;wv]
  unsigned short* wob   = (unsigned short*)(ws + (80ll << 20));    // 32MB bf16 wo
  unsigned short* qr    = (unsigned short*)(ws + (112ll << 20));   // 32MB q roped bf16
  unsigned short* kr    = (unsigned short*)(ws + (144ll << 20));   // 8MB  k roped bf16
  unsigned short* vb_   = (unsigned short*)(ws + (152ll << 20));   // 8MB  v bf16
  unsigned short* ao    = (unsigned short*)(ws + (160ll << 20));   // 32MB attn out bf16

  cast_all_k<<<57344, 256, 0, stream>>>(x, wq, wk, wv, wo, xb, wqkv, wob);
  gemm8<true><<<dim3(24, 16), 512, 0, stream>>>(xb, wqkv, nullptr, pos, qr, kr, vb_, 6144, 4096);
  attn_k<<<dim3(4, 32, 4), 256, 0, stream>>>(qr, kr, vb_, ao);
  gemm8<false><<<dim3(16, 16), 512, 0, stream>>>(ao, wob, out, nullptr, nullptr, nullptr, nullptr, 4096, 4096);
}

// Round 2
// 810.725 us; speedup vs baseline: 1.0020x; 1.0020x over previous
//
#include <hip/hip_runtime.h>
#include <hip/hip_bf16.h>
#include <math.h>

#define T_TOK 4096
#define HID   4096
#define NHQ   32
#define NKVH  8
#define HDIM  128
#define SEQ   1024
#define NBATCH 4

typedef __attribute__((ext_vector_type(8))) short bf16x8;
typedef __attribute__((ext_vector_type(4))) float f32x4;

__device__ __forceinline__ unsigned short f2bf(float f) {
  union { float f; unsigned int u; } x; x.f = f;
  unsigned int r = x.u + 0x7FFFu + ((x.u >> 16) & 1u);
  return (unsigned short)(r >> 16);
}

// async global->LDS, 16B per lane. LDS dest must be wave-uniform base; HW adds lane*16.
#define GLOAD_LDS16(gp, lp)                                                        \
  __builtin_amdgcn_global_load_lds(                                                \
      (__attribute__((address_space(1))) void*)(unsigned long long)(const void*)(gp), \
      (__attribute__((address_space(3))) void*)(unsigned long long)(const void*)(lp), \
      16, 0, 0)

// ---------------- single fused cast fp32 -> bf16 for all 5 tensors -------------
__global__ __launch_bounds__(256) void cast_all_k(const float* __restrict__ x,
                                                  const float* __restrict__ wq,
                                                  const float* __restrict__ wk,
                                                  const float* __restrict__ wv,
                                                  const float* __restrict__ wo,
                                                  unsigned short* __restrict__ xb,
                                                  unsigned short* __restrict__ wqkv,
                                                  unsigned short* __restrict__ wob) {
  int i = blockIdx.x * 256 + threadIdx.x;  // float4 index, total 14680064
  const float* src; unsigned short* dst; int off;
  if (i < 4194304)       { src = x;  dst = xb;   off = i; }
  else if (i < 8388608)  { src = wq; dst = wqkv; off = i - 4194304; }
  else if (i < 9437184)  { src = wk; dst = wqkv + 16777216; off = i - 8388608; }
  else if (i < 10485760) { src = wv; dst = wqkv + 20971520; off = i - 9437184; }
  else                   { src = wo; dst = wob;  off = i - 10485760; }
  float4 f = ((const float4*)src)[off];
  ushort4 o;
  o.x = f2bf(f.x); o.y = f2bf(f.y); o.z = f2bf(f.z); o.w = f2bf(f.w);
  ((ushort4*)dst)[off] = o;
}

// ---------------- GEMM: C[M,N] = A[M,K] @ B[N,K]^T (bf16 in) ------------------
// Tile 256x128, BK=64, 512 thr = 8 waves (4M x 2N), 16x16x32 MFMA.
// Wave: 64 rows (4 M-frags) x 64 cols (4 N-frags interleaved: wn*32+{0,16} and +64)
// so RoPE pair (d, d+64) lives in-lane at frags nf / nf+2.
// LDS: 3-slot ring (A 32KB + B 16KB per slot = 144KB). m201 st_16x32 geometry:
// [row][64 shorts] 128B rows; byte ^= ((row>>2)&1)<<5 (chunk-bit1 ^ row-bit2).
// Frag read: row = base + (lane&15), chunk = ks*4 + (lane>>4)  (measured
// conflict-free pattern). Writes linear via global_load_lds with pre-swizzled
// global source (rule 21: same involution on source and read).
// Schedule: 2 phases/K-tile, each {ds_reads || stage -> barrier -> setprio+16 MFMA}.
// Stage tile t+2 during tile t (ring-3 => no WAR). One counted vmcnt(6) per
// K-tile: retires exactly tile t+1's 6 loads, leaves tile t+2's 6 in flight.
template<bool FUSED>
__global__ __launch_bounds__(512, 2) void gemm8(const unsigned short* __restrict__ A,
                                                const unsigned short* __restrict__ B,
                                                float* __restrict__ C,
                                                const int* __restrict__ pos,
                                                unsigned short* __restrict__ qr,
                                                unsigned short* __restrict__ kr,
                                                unsigned short* __restrict__ vbuf,
                                                int N, int K) {
  __shared__ unsigned short As[3][16384];  // 96 KB: 3 x [256][64]
  __shared__ unsigned short Bs[3][8192];   // 48 KB: 3 x [128][64]
  const int tid  = threadIdx.x;
  const int lane = tid & 63;
  const int wave = tid >> 6;
  const int m16  = lane & 15;
  const int quad = lane >> 4;
  const int wm   = wave >> 1;   // 0..3: M offset wm*64
  const int wn   = wave & 1;    // 0..1: N frag base wn*32 (+16, +64, +80)

  // XCD-aware swizzle (nwg % 8 == 0 for both launches: 768 and 512)
  const int gx = gridDim.x;
  const int nwg = gx * gridDim.y;
  const int orig = blockIdx.y * gx + blockIdx.x;
  const int swz = (orig & 7) * (nwg >> 3) + (orig >> 3);
  const long rowBase = (long)(swz / gx) * 256;
  const long colBase = (long)(swz % gx) * 128;

  // staging: thread t stages 16B unit u = call*512 + tid  (row = u>>3, clin = u&7)
  // logical k-chunk = clin ^ (rowbit2<<1); rowbit2 = (tid>>5)&1 (call bases %64==0)
  const long Kl = K;
  const int sck = ((tid & 7) ^ (((tid >> 5) & 1) << 1)) * 8;
  const unsigned short* sA = A + (rowBase + (tid >> 3)) * Kl + sck;
  const unsigned short* sB = B + (colBase + (tid >> 3)) * Kl + sck;
  const int dofs = wave * 512;   // shorts; + call*4096

#define STG_A01(sl_, ko_) { GLOAD_LDS16(sA + (ko_),           &As[sl_][dofs]);          \
                            GLOAD_LDS16(sA + (ko_) + 64*Kl,   &As[sl_][4096 + dofs]); }
#define STG_A23(sl_, ko_) { GLOAD_LDS16(sA + (ko_) + 128*Kl,  &As[sl_][8192 + dofs]);   \
                            GLOAD_LDS16(sA + (ko_) + 192*Kl,  &As[sl_][12288 + dofs]); }
#define STG_B01(sl_, ko_) { GLOAD_LDS16(sB + (ko_),           &Bs[sl_][dofs]);          \
                            GLOAD_LDS16(sB + (ko_) + 64*Kl,   &Bs[sl_][4096 + dofs]); }

  // frag reads: m201 pattern. row&4 == m16&4 (all bases 16-aligned).
#define RDA(dv_, mfr_, ks_) {                                                     \
    int row_ = wm * 64 + (mfr_) * 16 + m16;                                       \
    dv_ = *(const bf16x8*)(Aq + row_ * 64 + ((((ks_)*4 + quad)*8) ^ ((row_ & 4) << 2))); }
#define RDB(dv_, nf_, ks_) {                                                      \
    int row_ = wn * 32 + ((nf_) & 1) * 16 + ((nf_) >> 1) * 64 + m16;              \
    dv_ = *(const bf16x8*)(Bq + row_ * 64 + ((((ks_)*4 + quad)*8) ^ ((row_ & 4) << 2))); }

  f32x4 acc[4][4] = {};   // [mf][nf]
  const int nt = K >> 6;  // K-tiles of 64

  // prologue: stage tiles 0,1 (6 loads each); tile0 landed, tile1 in flight
  STG_A01(0, 0); STG_A23(0, 0); STG_B01(0, 0);
  STG_A01(1, 64); STG_A23(1, 64); STG_B01(1, 64);
  asm volatile("s_waitcnt vmcnt(6)" ::: "memory");
  __builtin_amdgcn_s_barrier();

  int sl = 0;
  for (int t = 0; t < nt; ++t) {
    const unsigned short* Aq = &As[sl][0];
    const unsigned short* Bq = &Bs[sl][0];
    const int s2 = sl >= 1 ? sl - 1 : 2;        // (sl+2)%3
    const bool doStage = (t + 2) < nt;
    const long ko = (long)(t + 2) * 64;

    bf16x8 af[2][2], bf[4][2];
    // -------- phase 1: mf {0,1} x nf {0..3}, 12 ds_reads, stage A-half --------
#pragma unroll
    for (int mf = 0; mf < 2; ++mf)
#pragma unroll
      for (int ks = 0; ks < 2; ++ks) RDA(af[mf][ks], mf, ks);
#pragma unroll
    for (int nf = 0; nf < 4; ++nf)
#pragma unroll
      for (int ks = 0; ks < 2; ++ks) RDB(bf[nf][ks], nf, ks);
    if (doStage) STG_A01(s2, ko);
    asm volatile("s_waitcnt lgkmcnt(8)" ::: "memory");
    __builtin_amdgcn_s_barrier();
    __builtin_amdgcn_s_setprio(1);
#pragma unroll
    for (int mf = 0; mf < 2; ++mf)
#pragma unroll
      for (int nf = 0; nf < 4; ++nf)
#pragma unroll
        for (int ks = 0; ks < 2; ++ks)
          acc[mf][nf] = __builtin_amdgcn_mfma_f32_16x16x32_bf16(af[mf][ks], bf[nf][ks], acc[mf][nf], 0, 0, 0);
    __builtin_amdgcn_s_setprio(0);
    __builtin_amdgcn_s_barrier();

    // -------- phase 2: mf {2,3} (B kept in regs), 4 ds_reads, stage rest -----
#pragma unroll
    for (int mf = 0; mf < 2; ++mf)
#pragma unroll
      for (int ks = 0; ks < 2; ++ks) RDA(af[mf][ks], 2 + mf, ks);
    if (doStage) { STG_A23(s2, ko); STG_B01(s2, ko); }
    // retire exactly tile t+1's 6 loads; tile t+2's 6 stay in flight
    if (doStage)         asm volatile("s_waitcnt vmcnt(6)" ::: "memory");
    else if (t + 1 < nt) asm volatile("s_waitcnt vmcnt(0)" ::: "memory");
    __builtin_amdgcn_s_barrier();
    __builtin_amdgcn_s_setprio(1);
#pragma unroll
    for (int mf = 0; mf < 2; ++mf)
#pragma unroll
      for (int nf = 0; nf < 4; ++nf)
#pragma unroll
        for (int ks = 0; ks < 2; ++ks)
          acc[2 + mf][nf] = __builtin_amdgcn_mfma_f32_16x16x32_bf16(af[mf][ks], bf[nf][ks], acc[2 + mf][nf], 0, 0, 0);
    __builtin_amdgcn_s_setprio(0);
    __builtin_amdgcn_s_barrier();

    sl = sl == 2 ? 0 : sl + 1;
  }

  if (!FUSED) {
#pragma unroll
    for (int mf = 0; mf < 4; ++mf)
#pragma unroll
      for (int nf = 0; nf < 4; ++nf) {
        long c = colBase + wn * 32 + (nf & 1) * 16 + (nf >> 1) * 64 + m16;
#pragma unroll
        for (int reg = 0; reg < 4; ++reg) {
          long row = rowBase + wm * 64 + mf * 16 + quad * 4 + reg;
          C[row * N + c] = acc[mf][nf][reg];
        }
      }
    return;
  }

  // ---- fused epilogue: RoPE (q/k) or plain (v), bf16 scatter ----
  const int n0 = (int)colBase;   // 128-aligned head window
  unsigned short* dst;
  int rstride, colofs;
  bool dorope;
  if (n0 < 4096)       { dst = qr;   rstride = NHQ * HDIM;  colofs = n0;        dorope = true; }
  else if (n0 < 5120)  { dst = kr;   rstride = NKVH * HDIM; colofs = n0 - 4096; dorope = true; }
  else                 { dst = vbuf; rstride = NKVH * HDIM; colofs = n0 - 5120; dorope = false; }
  const float c0 = -13.287712379549449f / 64.0f;  // -log2(10000)/64
  float fA[2], fB[2];
#pragma unroll
  for (int e = 0; e < 2; ++e) {
    int d = wn * 32 + e * 16 + m16;
    fA[e] = exp2f(c0 * (float)(d >> 1));
    fB[e] = exp2f(c0 * (float)((d >> 1) + 32));
  }
#pragma unroll
  for (int mf = 0; mf < 4; ++mf) {
#pragma unroll
    for (int reg = 0; reg < 4; ++reg) {
      int grow = (int)rowBase + wm * 64 + mf * 16 + quad * 4 + reg;
      unsigned short* drow = dst + (long)grow * rstride + colofs;
      if (dorope) {
        int p = pos[grow];
        p = p < 0 ? 0 : (p > SEQ - 1 ? SEQ - 1 : p);
        float pf = (float)p;
#pragma unroll
        for (int e = 0; e < 2; ++e) {
          int d = wn * 32 + e * 16 + m16;
          float lo = acc[mf][e][reg], hi = acc[mf][e + 2][reg];
          float s1, cc1, s2, cc2;
          __sincosf(pf * fA[e], &s1, &cc1);
          __sincosf(pf * fB[e], &s2, &cc2);
          drow[d]      = f2bf(lo * cc1 - hi * s1);
          drow[d + 64] = f2bf(hi * cc2 + lo * s2);
        }
      } else {
#pragma unroll
        for (int e = 0; e < 2; ++e) {
          int d = wn * 32 + e * 16 + m16;
          drow[d]      = f2bf(acc[mf][e][reg]);
          drow[d + 64] = f2bf(acc[mf][e + 2][reg]);
        }
      }
    }
  }
}

// ---------------- Flash attention (causal, GQA), bf16 MFMA ----------------
#define ATT_SCALE_L2 0.12754227022f  // (1/sqrt(128)) * log2(e)
__global__ __launch_bounds__(256) void attn_k(const unsigned short* __restrict__ Qp,
                                              const unsigned short* __restrict__ Kp,
                                              const unsigned short* __restrict__ Vp,
                                              unsigned short* __restrict__ Op) {
  const int pr = blockIdx.x, h = blockIdx.y, b = blockIdx.z;
  const int kvh = h >> 2;
  const int tid = threadIdx.x, wave = tid >> 6, lane = tid & 63;
  const int m16 = lane & 15, quad = lane >> 4;

  __shared__ unsigned short Ks[64][128];   // [key][d], 16 chunks/row, 3-bit xor swizzle
  __shared__ unsigned short Vt[128][64];   // [d][key], 8 chunks/row, additive rotation
  __shared__ unsigned short Ps[4][32][64]; // per-wave P, additive rotation

  for (int pass = 0; pass < 2; ++pass) {
    const int qt = pass ? pr : (7 - pr);
    const int qbase = qt * 128;
    const int wq_lo = qbase + wave * 32;

    bf16x8 qa[2][4];
#pragma unroll
    for (int i = 0; i < 2; ++i) {
      const unsigned short* qrow =
          Qp + (long)(b * SEQ + wq_lo + i * 16 + m16) * (NHQ * HDIM) + h * HDIM;
#pragma unroll
      for (int kk = 0; kk < 4; ++kk)
        qa[i][kk] = *(const bf16x8*)(qrow + kk * 32 + quad * 8);
    }

    f32x4 o[2][8] = {};
    float mrow[2][4], lrow[2][4];
#pragma unroll
    for (int i = 0; i < 2; ++i)
#pragma unroll
      for (int r = 0; r < 4; ++r) { mrow[i][r] = -1e30f; lrow[i][r] = 0.f; }

    const int nkt = qt * 2 + 2;
    for (int kt = 0; kt < nkt; ++kt) {
      __syncthreads();
      const unsigned short* Kbase =
          Kp + (long)(b * SEQ + kt * 64) * (NKVH * HDIM) + kvh * HDIM;
      const unsigned short* Vbase =
          Vp + (long)(b * SEQ + kt * 64) * (NKVH * HDIM) + kvh * HDIM;
#pragma unroll
      for (int it = 0; it < 4; ++it) {
        int c = it * 256 + tid;
        int row = c >> 4, psg = c & 15;
        int sg = (psg & 8) | ((psg & 7) ^ (row & 7));
        GLOAD_LDS16(Kbase + row * (NKVH * HDIM) + sg * 8,
                    ((unsigned short*)Ks) + (it * 256 + wave * 64) * 8);
      }
#pragma unroll
      for (int it = 0; it < 4; ++it) {
        int seg = it * 4 + wave;  // wave-uniform
        uint4 dv = *(const uint4*)(Vbase + lane * (NKVH * HDIM) + seg * 8);
        const unsigned short* pv = (const unsigned short*)&dv;
#pragma unroll
        for (int e = 0; e < 8; ++e) {
          int d = seg * 8 + e;
          Vt[d][((((lane >> 3) + d) & 7) * 8) + (lane & 7)] = pv[e];
        }
      }
      __syncthreads();

      const bool active = (kt * 64) <= (wq_lo + 31);
      if (active) {
        f32x4 s4[2][4] = {};
#pragma unroll
        for (int kk = 0; kk < 4; ++kk) {
          bf16x8 kbf[4];
#pragma unroll
          for (int j = 0; j < 4; ++j) {
            int row = j * 16 + m16;
            int cl = kk * 4 + quad;
            int ps = (cl & 8) | ((cl & 7) ^ (row & 7));
            kbf[j] = *(const bf16x8*)(&Ks[row][ps * 8]);
          }
#pragma unroll
          for (int i = 0; i < 2; ++i)
#pragma unroll
            for (int j = 0; j < 4; ++j)
              s4[i][j] = __builtin_amdgcn_mfma_f32_16x16x32_bf16(qa[i][kk], kbf[j], s4[i][j], 0, 0, 0);
        }
        const bool full = (kt * 64 + 63) <= wq_lo;
#pragma unroll
        for (int i = 0; i < 2; ++i) {
#pragma unroll
          for (int r = 0; r < 4; ++r) {
            const int qrow = i * 16 + quad * 4 + r;
            const int qi = qbase + wave * 32 + qrow;
            float v[4];
#pragma unroll
            for (int j = 0; j < 4; ++j) {
              v[j] = s4[i][j][r] * ATT_SCALE_L2;
              if (!full && (kt * 64 + j * 16 + m16 > qi)) v[j] = -1e30f;
            }
            float mx = fmaxf(fmaxf(v[0], v[1]), fmaxf(v[2], v[3]));
            mx = fmaxf(mx, __shfl_xor(mx, 1));
            mx = fmaxf(mx, __shfl_xor(mx, 2));
            mx = fmaxf(mx, __shfl_xor(mx, 4));
            mx = fmaxf(mx, __shfl_xor(mx, 8));
            float mold = mrow[i][r];
            float mnew = fmaxf(mold, mx);
            float alpha = exp2f(mold - mnew);
            float rs = 0.f;
#pragma unroll
            for (int j = 0; j < 4; ++j) {
              float pj = exp2f(v[j] - mnew);
              rs += pj;
              int col = j * 16 + m16;
              Ps[wave][qrow][((((col >> 3) + qrow) & 7) * 8) + (col & 7)] = f2bf(pj);
            }
            rs += __shfl_xor(rs, 1); rs += __shfl_xor(rs, 2);
            rs += __shfl_xor(rs, 4); rs += __shfl_xor(rs, 8);
            lrow[i][r] = lrow[i][r] * alpha + rs;
            mrow[i][r] = mnew;
#pragma unroll
            for (int n = 0; n < 8; ++n) o[i][n][r] *= alpha;
          }
        }
#pragma unroll
        for (int kk = 0; kk < 2; ++kk) {
          bf16x8 pa[2], vb[8];
#pragma unroll
          for (int i = 0; i < 2; ++i) {
            int row = i * 16 + m16;
            pa[i] = *(const bf16x8*)(&Ps[wave][row][(((kk * 4 + quad) + row) & 7) * 8]);
          }
#pragma unroll
          for (int n = 0; n < 8; ++n) {
            int row = n * 16 + m16;
            vb[n] = *(const bf16x8*)(&Vt[row][(((kk * 4 + quad) + row) & 7) * 8]);
          }
#pragma unroll
          for (int i = 0; i < 2; ++i)
#pragma unroll
            for (int n = 0; n < 8; ++n)
              o[i][n] = __builtin_amdgcn_mfma_f32_16x16x32_bf16(pa[i], vb[n], o[i][n], 0, 0, 0);
        }
      }
    }
#pragma unroll
    for (int i = 0; i < 2; ++i) {
#pragma unroll
      for (int r = 0; r < 4; ++r) {
        float inv = 1.0f / lrow[i][r];
        unsigned short* orow =
            Op + (long)(b * SEQ + wq_lo + i * 16 + quad * 4 + r) * (NHQ * HDIM) + h * HDIM;
#pragma unroll
        for (int n = 0; n < 8; ++n)
          orow[n * 16 + m16] = f2bf(o[i][n][r] * inv);
      }
    }
  }
}

// ---------------- launch ----------------
extern "C" void kernel_launch(void* const* d_in, const int* in_sizes, int n_in,
                              void* d_out, int out_size, void* d_ws, size_t ws_size,
                              hipStream_t stream) {
  (void)in_sizes; (void)n_in; (void)out_size; (void)ws_size;
  const float* x  = (const float*)d_in[0];
  const int* pos  = (const int*)d_in[1];
  const float* wq = (const float*)d_in[3];
  const float* wk = (const float*)d_in[4];
  const float* wv = (const float*)d_in[5];
  const float* wo = (const float*)d_in[6];
  float* out = (float*)d_out;

  char* ws = (char*)d_ws;
  unsigned short* xb    = (unsigned short*)(ws);                   // 32MB bf16 x
  unsigned short* wqkv  = (unsigned short*)(ws + (32ll << 20));    // 48MB bf16 [wq;wk;wv]
  unsigned short* wob   = (unsigned short*)(ws + (80ll << 20));    // 32MB bf16 wo
  unsigned short* qr    = (unsigned short*)(ws + (112ll << 20));   // 32MB q roped bf16
  unsigned short* kr    = (unsigned short*)(ws + (144ll << 20));   // 8MB  k roped bf16
  unsigned short* vb_   = (unsigned short*)(ws + (152ll << 20));   // 8MB  v bf16
  unsigned short* ao    = (unsigned short*)(ws + (160ll << 20));   // 32MB attn out bf16

  cast_all_k<<<57344, 256, 0, stream>>>(x, wq, wk, wv, wo, xb, wqkv, wob);
  gemm8<true><<<dim3(48, 16), 512, 0, stream>>>(xb, wqkv, nullptr, pos, qr, kr, vb_, 6144, 4096);
  attn_k<<<dim3(4, 32, 4), 256, 0, stream>>>(qr, kr, vb_, ao);
  gemm8<false><<<dim3(32, 16), 512, 0, stream>>>(ao, wob, out, nullptr, nullptr, nullptr, nullptr, 4096, 4096);
}

// Round 3
// 753.958 us; speedup vs baseline: 1.0774x; 1.0753x over previous
//
#include <hip/hip_runtime.h>
#include <hip/hip_bf16.h>
#include <math.h>

#define T_TOK 4096
#define HID   4096
#define NHQ   32
#define NKVH  8
#define HDIM  128
#define SEQ   1024
#define NBATCH 4

typedef __attribute__((ext_vector_type(8))) short bf16x8;
typedef __attribute__((ext_vector_type(4))) float f32x4;

__device__ __forceinline__ unsigned short f2bf(float f) {
  union { float f; unsigned int u; } x; x.f = f;
  unsigned int r = x.u + 0x7FFFu + ((x.u >> 16) & 1u);
  return (unsigned short)(r >> 16);
}

// async global->LDS, 16B per lane. LDS dest must be wave-uniform base; HW adds lane*16.
#define GLOAD_LDS16(gp, lp)                                                        \
  __builtin_amdgcn_global_load_lds(                                                \
      (__attribute__((address_space(1))) void*)(unsigned long long)(const void*)(gp), \
      (__attribute__((address_space(3))) void*)(unsigned long long)(const void*)(lp), \
      16, 0, 0)

// ---------------- single fused cast fp32 -> bf16 for all 5 tensors -------------
__global__ __launch_bounds__(256) void cast_all_k(const float* __restrict__ x,
                                                  const float* __restrict__ wq,
                                                  const float* __restrict__ wk,
                                                  const float* __restrict__ wv,
                                                  const float* __restrict__ wo,
                                                  unsigned short* __restrict__ xb,
                                                  unsigned short* __restrict__ wqkv,
                                                  unsigned short* __restrict__ wob) {
  int i = blockIdx.x * 256 + threadIdx.x;  // float4 index, total 14680064
  const float* src; unsigned short* dst; int off;
  if (i < 4194304)       { src = x;  dst = xb;   off = i; }
  else if (i < 8388608)  { src = wq; dst = wqkv; off = i - 4194304; }
  else if (i < 9437184)  { src = wk; dst = wqkv + 16777216; off = i - 8388608; }
  else if (i < 10485760) { src = wv; dst = wqkv + 20971520; off = i - 9437184; }
  else                   { src = wo; dst = wob;  off = i - 10485760; }
  float4 f = ((const float4*)src)[off];
  ushort4 o;
  o.x = f2bf(f.x); o.y = f2bf(f.y); o.z = f2bf(f.z); o.w = f2bf(f.w);
  ((ushort4*)dst)[off] = o;
}

// ---------------- GEMM: C[M,N] = A[M,K] @ B[N,K]^T (bf16 in) ------------------
// Tile 256x128, BK=64, 512 thr = 8 waves (4M x 2N), 16x16x32 MFMA.
// Wave: 64 rows x 64 cols, N-frags nf: col = wn*32 + (nf&1)*16 + (nf>>1)*64
// so RoPE pair (d, d+64) lives in-lane at frags nf / nf+2.
// LDS: A dbuf-2 (2x32KB), B ring-4 (4x16KB) = 128KB. Buffer slots are
// COMPILE-TIME (4-tile unrolled iter) so every ds_read folds to base+imm.
// Swizzle (3-bit): 16B-slot = chunk ^ (row&7); row&7 == m16&7 for all frag
// reads -> per-thread loop-invariant offsets. Source pre-swizzled (rule 21).
// Schedule per tile: P1 {12 ds_read || stage SB(X+2) -> bar -> lgkm0 ->
// prio+16 MFMA -> bar}, P2 {4 ds_read || stage SA(X+2) -> bar -> lgkm0 ->
// prio+16 MFMA -> vmcnt(6) -> bar}. vmcnt(6) retires exactly tile X+1's 6
// loads (issued >=2 phases earlier), keeps tile X+2's 6 in flight. No drains.
template<bool FUSED>
__global__ __launch_bounds__(512, 2) void gemm8(const unsigned short* __restrict__ A,
                                                const unsigned short* __restrict__ B,
                                                float* __restrict__ C,
                                                const int* __restrict__ pos,
                                                unsigned short* __restrict__ qr,
                                                unsigned short* __restrict__ kr,
                                                unsigned short* __restrict__ vbuf,
                                                int N, int K) {
  __shared__ unsigned short AL[2][16384];  // 64 KB: 2 x [256 rows][64 shorts]
  __shared__ unsigned short BL[4][8192];   // 64 KB: 4 x [128 rows][64 shorts]
  const int tid  = threadIdx.x;
  const int lane = tid & 63;
  const int wave = tid >> 6;
  const int m16  = lane & 15;
  const int quad = lane >> 4;
  const int wm   = wave >> 1;   // 0..3: rows wm*64..+63
  const int wn   = wave & 1;    // 0..1

  // XCD-aware swizzle (nwg % 8 == 0: 768 and 512)
  const int gx = gridDim.x;
  const int nwg = gx * gridDim.y;
  const int orig = blockIdx.y * gx + blockIdx.x;
  const int swz = (orig & 7) * (nwg >> 3) + (orig >> 3);
  const long rowBase = (long)(swz / gx) * 256;
  const long colBase = (long)(swz % gx) * 128;

  // ---- per-thread loop-invariant LDS read offsets (shorts) ----
  // frag read: row = base + m16, slot = (ks*4+quad) ^ (m16&7)
  int aoff[2], boff[2];
#pragma unroll
  for (int ks = 0; ks < 2; ++ks) {
    int sx = ((ks * 4 + quad) ^ (m16 & 7)) * 8;
    aoff[ks] = (wm * 64 + m16) * 64 + sx;
    boff[ks] = (wn * 32 + m16) * 64 + sx;
  }

  // ---- staging source (inverse swizzle): thread t covers 64 rows/call ----
  // unit u=t: region row = t>>3 (+64*h), slot = t&7, chunk = (t&7)^((t>>3)&7)
  const long Kl = K;
  const int sck = ((tid & 7) ^ ((tid >> 3) & 7)) * 8;
  const unsigned short* gA = A + (rowBase + (tid >> 3)) * Kl + sck;
  const unsigned short* gB = B + (colBase + (tid >> 3)) * Kl + sck;
  const int dofs = wave * 512;  // + h*4096

  // stage ops (per-thread): SB = 2 gloads, SA = 4 gloads
#define STG_B(slot_, ko_) { GLOAD_LDS16(gB + (ko_),            &BL[slot_][dofs]);         \
                            GLOAD_LDS16(gB + (ko_) + 64 * Kl,  &BL[slot_][4096 + dofs]); }
#define STG_A(slot_, ko_) { GLOAD_LDS16(gA + (ko_),            &AL[slot_][dofs]);         \
                            GLOAD_LDS16(gA + (ko_) + 64 * Kl,  &AL[slot_][4096 + dofs]);  \
                            GLOAD_LDS16(gA + (ko_) + 128 * Kl, &AL[slot_][8192 + dofs]);  \
                            GLOAD_LDS16(gA + (ko_) + 192 * Kl, &AL[slot_][12288 + dofs]); }

  f32x4 acc[4][4] = {};   // [mf][nf]

  // prologue: stage tiles 0,1. FIFO: SB0(2) SA0(4) SB1(2) SA1(4) = 12 loads.
  STG_B(0, 0); STG_A(0, 0); STG_B(1, 64); STG_A(1, 64);
  asm volatile("s_waitcnt vmcnt(6)" ::: "memory");  // tile0's 6 landed
  __builtin_amdgcn_s_barrier();

  // 64 K-tiles, 4 per iter (A buf = u&1, B slot = u, both compile-time)
  for (int it = 0; it < 16; ++it) {
#pragma unroll
    for (int u = 0; u < 4; ++u) {
      const int X = it * 4 + u;
      const int kn = ((X + 2) & 63) << 6;   // staged k-offset (wrap-safe tail)
      bf16x8 af[4][2], bf01[2][2], bf23[2][2];

      // ---------- P1: 12 ds_read + stage SB(X+2) ----------
#pragma unroll
      for (int mf = 0; mf < 4; ++mf)
#pragma unroll
        for (int ks = 0; ks < 2; ++ks)
          af[mf][ks] = *(const bf16x8*)(&AL[u & 1][aoff[ks] + mf * 1024]);
#pragma unroll
      for (int nf = 0; nf < 2; ++nf)
#pragma unroll
        for (int ks = 0; ks < 2; ++ks)
          bf01[nf][ks] = *(const bf16x8*)(&BL[u][boff[ks] + nf * 1024]);
      STG_B((u + 2) & 3, kn);
      asm volatile("s_waitcnt lgkmcnt(8)" ::: "memory");
      __builtin_amdgcn_s_barrier();
      asm volatile("s_waitcnt lgkmcnt(0)" ::: "memory");
      __builtin_amdgcn_s_setprio(1);
#pragma unroll
      for (int mf = 0; mf < 4; ++mf)
#pragma unroll
        for (int nf = 0; nf < 2; ++nf)
#pragma unroll
          for (int ks = 0; ks < 2; ++ks)
            acc[mf][nf] = __builtin_amdgcn_mfma_f32_16x16x32_bf16(af[mf][ks], bf01[nf][ks], acc[mf][nf], 0, 0, 0);
      __builtin_amdgcn_s_setprio(0);
      __builtin_amdgcn_s_barrier();

      // ---------- P2: 4 ds_read + stage SA(X+2), vmcnt(6) ----------
#pragma unroll
      for (int nf = 0; nf < 2; ++nf)
#pragma unroll
        for (int ks = 0; ks < 2; ++ks)
          bf23[nf][ks] = *(const bf16x8*)(&BL[u][boff[ks] + nf * 1024 + 4096]);
      STG_A(u & 1, kn);
      __builtin_amdgcn_s_barrier();
      asm volatile("s_waitcnt lgkmcnt(0)" ::: "memory");
      __builtin_amdgcn_s_setprio(1);
#pragma unroll
      for (int mf = 0; mf < 4; ++mf)
#pragma unroll
        for (int nf = 0; nf < 2; ++nf)
#pragma unroll
          for (int ks = 0; ks < 2; ++ks)
            acc[mf][nf + 2] = __builtin_amdgcn_mfma_f32_16x16x32_bf16(af[mf][ks], bf23[nf][ks], acc[mf][nf + 2], 0, 0, 0);
      __builtin_amdgcn_s_setprio(0);
      // retire tile X+1's 6 loads; keep tile X+2's 6 in flight
      asm volatile("s_waitcnt vmcnt(6)" ::: "memory");
      __builtin_amdgcn_s_barrier();
    }
  }

  if (!FUSED) {
#pragma unroll
    for (int mf = 0; mf < 4; ++mf)
#pragma unroll
      for (int nf = 0; nf < 4; ++nf) {
        long c = colBase + wn * 32 + (nf & 1) * 16 + (nf >> 1) * 64 + m16;
#pragma unroll
        for (int reg = 0; reg < 4; ++reg) {
          long row = rowBase + wm * 64 + mf * 16 + quad * 4 + reg;
          C[row * N + c] = acc[mf][nf][reg];
        }
      }
    return;
  }

  // ---- fused epilogue: RoPE (q/k) or plain (v), bf16 scatter ----
  const int n0 = (int)colBase;   // 128-aligned head window
  unsigned short* dst;
  int rstride, colofs;
  bool dorope;
  if (n0 < 4096)       { dst = qr;   rstride = NHQ * HDIM;  colofs = n0;        dorope = true; }
  else if (n0 < 5120)  { dst = kr;   rstride = NKVH * HDIM; colofs = n0 - 4096; dorope = true; }
  else                 { dst = vbuf; rstride = NKVH * HDIM; colofs = n0 - 5120; dorope = false; }
  const float c0 = -13.287712379549449f / 64.0f;  // -log2(10000)/64
  float fA[2], fB[2];
#pragma unroll
  for (int e = 0; e < 2; ++e) {
    int d = wn * 32 + e * 16 + m16;
    fA[e] = exp2f(c0 * (float)(d >> 1));
    fB[e] = exp2f(c0 * (float)((d >> 1) + 32));
  }
#pragma unroll
  for (int mf = 0; mf < 4; ++mf) {
#pragma unroll
    for (int reg = 0; reg < 4; ++reg) {
      int grow = (int)rowBase + wm * 64 + mf * 16 + quad * 4 + reg;
      unsigned short* drow = dst + (long)grow * rstride + colofs;
      if (dorope) {
        int p = pos[grow];
        p = p < 0 ? 0 : (p > SEQ - 1 ? SEQ - 1 : p);
        float pf = (float)p;
#pragma unroll
        for (int e = 0; e < 2; ++e) {
          int d = wn * 32 + e * 16 + m16;
          float lo = acc[mf][e][reg], hi = acc[mf][e + 2][reg];
          float s1, cc1, s2, cc2;
          __sincosf(pf * fA[e], &s1, &cc1);
          __sincosf(pf * fB[e], &s2, &cc2);
          drow[d]      = f2bf(lo * cc1 - hi * s1);
          drow[d + 64] = f2bf(hi * cc2 + lo * s2);
        }
      } else {
#pragma unroll
        for (int e = 0; e < 2; ++e) {
          int d = wn * 32 + e * 16 + m16;
          drow[d]      = f2bf(acc[mf][e][reg]);
          drow[d + 64] = f2bf(acc[mf][e + 2][reg]);
        }
      }
    }
  }
}

// ---------------- Flash attention (causal, GQA), bf16 MFMA ----------------
#define ATT_SCALE_L2 0.12754227022f  // (1/sqrt(128)) * log2(e)
__global__ __launch_bounds__(256) void attn_k(const unsigned short* __restrict__ Qp,
                                              const unsigned short* __restrict__ Kp,
                                              const unsigned short* __restrict__ Vp,
                                              unsigned short* __restrict__ Op) {
  const int pr = blockIdx.x, h = blockIdx.y, b = blockIdx.z;
  const int kvh = h >> 2;
  const int tid = threadIdx.x, wave = tid >> 6, lane = tid & 63;
  const int m16 = lane & 15, quad = lane >> 4;

  __shared__ unsigned short Ks[64][128];   // [key][d], 16 chunks/row, 3-bit xor swizzle
  __shared__ unsigned short Vt[128][64];   // [d][key], 8 chunks/row, additive rotation
  __shared__ unsigned short Ps[4][32][64]; // per-wave P, additive rotation

  for (int pass = 0; pass < 2; ++pass) {
    const int qt = pass ? pr : (7 - pr);
    const int qbase = qt * 128;
    const int wq_lo = qbase + wave * 32;

    bf16x8 qa[2][4];
#pragma unroll
    for (int i = 0; i < 2; ++i) {
      const unsigned short* qrow =
          Qp + (long)(b * SEQ + wq_lo + i * 16 + m16) * (NHQ * HDIM) + h * HDIM;
#pragma unroll
      for (int kk = 0; kk < 4; ++kk)
        qa[i][kk] = *(const bf16x8*)(qrow + kk * 32 + quad * 8);
    }

    f32x4 o[2][8] = {};
    float mrow[2][4], lrow[2][4];
#pragma unroll
    for (int i = 0; i < 2; ++i)
#pragma unroll
      for (int r = 0; r < 4; ++r) { mrow[i][r] = -1e30f; lrow[i][r] = 0.f; }

    const int nkt = qt * 2 + 2;
    for (int kt = 0; kt < nkt; ++kt) {
      __syncthreads();
      const unsigned short* Kbase =
          Kp + (long)(b * SEQ + kt * 64) * (NKVH * HDIM) + kvh * HDIM;
      const unsigned short* Vbase =
          Vp + (long)(b * SEQ + kt * 64) * (NKVH * HDIM) + kvh * HDIM;
#pragma unroll
      for (int it = 0; it < 4; ++it) {
        int c = it * 256 + tid;
        int row = c >> 4, psg = c & 15;
        int sg = (psg & 8) | ((psg & 7) ^ (row & 7));
        GLOAD_LDS16(Kbase + row * (NKVH * HDIM) + sg * 8,
                    ((unsigned short*)Ks) + (it * 256 + wave * 64) * 8);
      }
#pragma unroll
      for (int it = 0; it < 4; ++it) {
        int seg = it * 4 + wave;  // wave-uniform
        uint4 dv = *(const uint4*)(Vbase + lane * (NKVH * HDIM) + seg * 8);
        const unsigned short* pv = (const unsigned short*)&dv;
#pragma unroll
        for (int e = 0; e < 8; ++e) {
          int d = seg * 8 + e;
          Vt[d][((((lane >> 3) + d) & 7) * 8) + (lane & 7)] = pv[e];
        }
      }
      __syncthreads();

      const bool active = (kt * 64) <= (wq_lo + 31);
      if (active) {
        f32x4 s4[2][4] = {};
#pragma unroll
        for (int kk = 0; kk < 4; ++kk) {
          bf16x8 kbf[4];
#pragma unroll
          for (int j = 0; j < 4; ++j) {
            int row = j * 16 + m16;
            int cl = kk * 4 + quad;
            int ps = (cl & 8) | ((cl & 7) ^ (row & 7));
            kbf[j] = *(const bf16x8*)(&Ks[row][ps * 8]);
          }
#pragma unroll
          for (int i = 0; i < 2; ++i)
#pragma unroll
            for (int j = 0; j < 4; ++j)
              s4[i][j] = __builtin_amdgcn_mfma_f32_16x16x32_bf16(qa[i][kk], kbf[j], s4[i][j], 0, 0, 0);
        }
        const bool full = (kt * 64 + 63) <= wq_lo;
#pragma unroll
        for (int i = 0; i < 2; ++i) {
#pragma unroll
          for (int r = 0; r < 4; ++r) {
            const int qrow = i * 16 + quad * 4 + r;
            const int qi = qbase + wave * 32 + qrow;
            float v[4];
#pragma unroll
            for (int j = 0; j < 4; ++j) {
              v[j] = s4[i][j][r] * ATT_SCALE_L2;
              if (!full && (kt * 64 + j * 16 + m16 > qi)) v[j] = -1e30f;
            }
            float mx = fmaxf(fmaxf(v[0], v[1]), fmaxf(v[2], v[3]));
            mx = fmaxf(mx, __shfl_xor(mx, 1));
            mx = fmaxf(mx, __shfl_xor(mx, 2));
            mx = fmaxf(mx, __shfl_xor(mx, 4));
            mx = fmaxf(mx, __shfl_xor(mx, 8));
            float mold = mrow[i][r];
            float mnew = fmaxf(mold, mx);
            float alpha = exp2f(mold - mnew);
            float rs = 0.f;
#pragma unroll
            for (int j = 0; j < 4; ++j) {
              float pj = exp2f(v[j] - mnew);
              rs += pj;
              int col = j * 16 + m16;
              Ps[wave][qrow][((((col >> 3) + qrow) & 7) * 8) + (col & 7)] = f2bf(pj);
            }
            rs += __shfl_xor(rs, 1); rs += __shfl_xor(rs, 2);
            rs += __shfl_xor(rs, 4); rs += __shfl_xor(rs, 8);
            lrow[i][r] = lrow[i][r] * alpha + rs;
            mrow[i][r] = mnew;
#pragma unroll
            for (int n = 0; n < 8; ++n) o[i][n][r] *= alpha;
          }
        }
#pragma unroll
        for (int kk = 0; kk < 2; ++kk) {
          bf16x8 pa[2], vb[8];
#pragma unroll
          for (int i = 0; i < 2; ++i) {
            int row = i * 16 + m16;
            pa[i] = *(const bf16x8*)(&Ps[wave][row][(((kk * 4 + quad) + row) & 7) * 8]);
          }
#pragma unroll
          for (int n = 0; n < 8; ++n) {
            int row = n * 16 + m16;
            vb[n] = *(const bf16x8*)(&Vt[row][(((kk * 4 + quad) + row) & 7) * 8]);
          }
#pragma unroll
          for (int i = 0; i < 2; ++i)
#pragma unroll
            for (int n = 0; n < 8; ++n)
              o[i][n] = __builtin_amdgcn_mfma_f32_16x16x32_bf16(pa[i], vb[n], o[i][n], 0, 0, 0);
        }
      }
    }
#pragma unroll
    for (int i = 0; i < 2; ++i) {
#pragma unroll
      for (int r = 0; r < 4; ++r) {
        float inv = 1.0f / lrow[i][r];
        unsigned short* orow =
            Op + (long)(b * SEQ + wq_lo + i * 16 + quad * 4 + r) * (NHQ * HDIM) + h * HDIM;
#pragma unroll
        for (int n = 0; n < 8; ++n)
          orow[n * 16 + m16] = f2bf(o[i][n][r] * inv);
      }
    }
  }
}

// ---------------- launch ----------------
extern "C" void kernel_launch(void* const* d_in, const int* in_sizes, int n_in,
                              void* d_out, int out_size, void* d_ws, size_t ws_size,
                              hipStream_t stream) {
  (void)in_sizes; (void)n_in; (void)out_size; (void)ws_size;
  const float* x  = (const float*)d_in[0];
  const int* pos  = (const int*)d_in[1];
  const float* wq = (const float*)d_in[3];
  const float* wk = (const float*)d_in[4];
  const float* wv = (const float*)d_in[5];
  const float* wo = (const float*)d_in[6];
  float* out = (float*)d_out;

  char* ws = (char*)d_ws;
  unsigned short* xb    = (unsigned short*)(ws);                   // 32MB bf16 x
  unsigned short* wqkv  = (unsigned short*)(ws + (32ll << 20));    // 48MB bf16 [wq;wk;wv]
  unsigned short* wob   = (unsigned short*)(ws + (80ll << 20));    // 32MB bf16 wo
  unsigned short* qr    = (unsigned short*)(ws + (112ll << 20));   // 32MB q roped bf16
  unsigned short* kr    = (unsigned short*)(ws + (144ll << 20));   // 8MB  k roped bf16
  unsigned short* vb_   = (unsigned short*)(ws + (152ll << 20));   // 8MB  v bf16
  unsigned short* ao    = (unsigned short*)(ws + (160ll << 20));   // 32MB attn out bf16

  cast_all_k<<<57344, 256, 0, stream>>>(x, wq, wk, wv, wo, xb, wqkv, wob);
  gemm8<true><<<dim3(48, 16), 512, 0, stream>>>(xb, wqkv, nullptr, pos, qr, kr, vb_, 6144, 4096);
  attn_k<<<dim3(4, 32, 4), 256, 0, stream>>>(qr, kr, vb_, ao);
  gemm8<false><<<dim3(32, 16), 512, 0, stream>>>(ao, wob, out, nullptr, nullptr, nullptr, nullptr, 4096, 4096);
}

// Round 4
// 744.415 us; speedup vs baseline: 1.0912x; 1.0128x over previous
//
#include <hip/hip_runtime.h>
#include <hip/hip_bf16.h>
#include <math.h>

#define T_TOK 4096
#define HID   4096
#define NHQ   32
#define NKVH  8
#define HDIM  128
#define SEQ   1024
#define NBATCH 4

typedef __attribute__((ext_vector_type(8))) short bf16x8;
typedef __attribute__((ext_vector_type(4))) float f32x4;

__device__ __forceinline__ unsigned short f2bf(float f) {
  union { float f; unsigned int u; } x; x.f = f;
  unsigned int r = x.u + 0x7FFFu + ((x.u >> 16) & 1u);
  return (unsigned short)(r >> 16);
}

// async global->LDS, 16B per lane. LDS dest must be wave-uniform base; HW adds lane*16.
#define GLOAD_LDS16(gp, lp)                                                        \
  __builtin_amdgcn_global_load_lds(                                                \
      (__attribute__((address_space(1))) void*)(unsigned long long)(const void*)(gp), \
      (__attribute__((address_space(3))) void*)(unsigned long long)(const void*)(lp), \
      16, 0, 0)

// ---------------- single fused cast fp32 -> bf16 for all 5 tensors -------------
__global__ __launch_bounds__(256) void cast_all_k(const float* __restrict__ x,
                                                  const float* __restrict__ wq,
                                                  const float* __restrict__ wk,
                                                  const float* __restrict__ wv,
                                                  const float* __restrict__ wo,
                                                  unsigned short* __restrict__ xb,
                                                  unsigned short* __restrict__ wqkv,
                                                  unsigned short* __restrict__ wob) {
  int i = blockIdx.x * 256 + threadIdx.x;  // float4 index, total 14680064
  const float* src; unsigned short* dst; int off;
  if (i < 4194304)       { src = x;  dst = xb;   off = i; }
  else if (i < 8388608)  { src = wq; dst = wqkv; off = i - 4194304; }
  else if (i < 9437184)  { src = wk; dst = wqkv + 16777216; off = i - 8388608; }
  else if (i < 10485760) { src = wv; dst = wqkv + 20971520; off = i - 9437184; }
  else                   { src = wo; dst = wob;  off = i - 10485760; }
  float4 f = ((const float4*)src)[off];
  ushort4 o;
  o.x = f2bf(f.x); o.y = f2bf(f.y); o.z = f2bf(f.z); o.w = f2bf(f.w);
  ((ushort4*)dst)[off] = o;
}

// ============== QKV GEMM (fused RoPE): C[4096,6144] = A @ B^T ==================
// Tile 256x128, BK=64, 8 waves (4M x 2N), 16x16x32 MFMA, ring-3 LDS both mats,
// ONE barrier per K-tile, ks-split register pipeline.
// Safety: all 16 ds_reads of tile t are consumed by MFMAs before the end-bar
// (=> retired); stage at t targets slot (t+2)%3 != t%3, (t+1)%3; skew < 1 tile.
// vmcnt(6) at tile end retires exactly tile t+1's 6 loads (FIFO), keeps t+2's
// 6 in flight across the barrier. Conflict-free swizzle verified R3 (0 confl).
__global__ __launch_bounds__(512, 2) void gemm_qkv(const unsigned short* __restrict__ A,
                                                   const unsigned short* __restrict__ B,
                                                   const int* __restrict__ pos,
                                                   unsigned short* __restrict__ qr,
                                                   unsigned short* __restrict__ kr,
                                                   unsigned short* __restrict__ vbuf) {
  const int K = 4096, nt = 64;
  __shared__ unsigned short AS[3][16384];  // 96 KB: [256 rows][64 shorts] per slot
  __shared__ unsigned short BS[3][8192];   // 48 KB: [128 rows][64 shorts] per slot
  const int tid  = threadIdx.x;
  const int lane = tid & 63;
  const int wave = tid >> 6;
  const int m16  = lane & 15;
  const int quad = lane >> 4;
  const int wm   = wave >> 1;   // 0..3: rows wm*64..+63
  const int wn   = wave & 1;    // 0..1

  // XCD-aware swizzle (nwg = 768, %8==0)
  const int gx = 48;
  const int orig = blockIdx.y * gx + blockIdx.x;
  const int swz = (orig & 7) * 96 + (orig >> 3);
  const long rowBase = (long)(swz / gx) * 256;
  const long colBase = (long)(swz % gx) * 128;

  // loop-invariant LDS frag read offsets (shorts): row=base+m16, slot=(ks*4+quad)^(m16&7)
  int aoff[2], boff[2];
#pragma unroll
  for (int ks = 0; ks < 2; ++ks) {
    int sx = ((ks * 4 + quad) ^ (m16 & 7)) * 8;
    aoff[ks] = (wm * 64 + m16) * 64 + sx;
    boff[ks] = (wn * 32 + m16) * 64 + sx;
  }

  // staging source (inverse swizzle), R3-verified
  const long Kl = K;
  const int sck = ((tid & 7) ^ ((tid >> 3) & 7)) * 8;
  const unsigned short* gA = A + (rowBase + (tid >> 3)) * Kl + sck;
  const unsigned short* gB = B + (colBase + (tid >> 3)) * Kl + sck;
  const int dofs = wave * 512;

#define STG_B(slot_, ko_) { GLOAD_LDS16(gB + (ko_),            &BS[slot_][dofs]);         \
                            GLOAD_LDS16(gB + (ko_) + 64 * Kl,  &BS[slot_][4096 + dofs]); }
#define STG_A(slot_, ko_) { GLOAD_LDS16(gA + (ko_),            &AS[slot_][dofs]);         \
                            GLOAD_LDS16(gA + (ko_) + 64 * Kl,  &AS[slot_][4096 + dofs]);  \
                            GLOAD_LDS16(gA + (ko_) + 128 * Kl, &AS[slot_][8192 + dofs]);  \
                            GLOAD_LDS16(gA + (ko_) + 192 * Kl, &AS[slot_][12288 + dofs]); }

  f32x4 acc[4][4] = {};   // [mf][nf]

  // prologue: stage tiles 0 (slot 0) and 1 (slot 1); 6 loads each
  STG_A(0, 0); STG_B(0, 0);
  STG_A(1, 64); STG_B(1, 64);
  asm volatile("s_waitcnt vmcnt(6)" ::: "memory");   // tile0 landed, tile1 in flight
  __builtin_amdgcn_s_barrier();

  for (int g = 0; g < 22; ++g) {
#pragma unroll
    for (int u = 0; u < 3; ++u) {
      const int t = g * 3 + u;
      if (t < nt) {
        const bool doStage = (t + 2) < nt;
        const long kn = (long)(t + 2) * 64;
        bf16x8 af[4][2], bfr[4][2];
        // ks=0 reads (8)
#pragma unroll
        for (int mf = 0; mf < 4; ++mf)
          af[mf][0] = *(const bf16x8*)(&AS[u][aoff[0] + mf * 1024]);
#pragma unroll
        for (int nf = 0; nf < 4; ++nf)
          bfr[nf][0] = *(const bf16x8*)(&BS[u][boff[0] + (nf & 1) * 1024 + (nf >> 1) * 4096]);
        // stage tile t+2 into slot (u+2)%3 (6 gloads)
        if (doStage) { STG_A((u + 2) % 3, kn); STG_B((u + 2) % 3, kn); }
        // ks=1 reads (8) — retire under ks=0 MFMAs (compiler fine-grained lgkm)
#pragma unroll
        for (int mf = 0; mf < 4; ++mf)
          af[mf][1] = *(const bf16x8*)(&AS[u][aoff[1] + mf * 1024]);
#pragma unroll
        for (int nf = 0; nf < 4; ++nf)
          bfr[nf][1] = *(const bf16x8*)(&BS[u][boff[1] + (nf & 1) * 1024 + (nf >> 1) * 4096]);
        __builtin_amdgcn_s_setprio(1);
#pragma unroll
        for (int mf = 0; mf < 4; ++mf)
#pragma unroll
          for (int nf = 0; nf < 4; ++nf)
            acc[mf][nf] = __builtin_amdgcn_mfma_f32_16x16x32_bf16(af[mf][0], bfr[nf][0], acc[mf][nf], 0, 0, 0);
#pragma unroll
        for (int mf = 0; mf < 4; ++mf)
#pragma unroll
          for (int nf = 0; nf < 4; ++nf)
            acc[mf][nf] = __builtin_amdgcn_mfma_f32_16x16x32_bf16(af[mf][1], bfr[nf][1], acc[mf][nf], 0, 0, 0);
        __builtin_amdgcn_s_setprio(0);
        if (doStage)        asm volatile("s_waitcnt vmcnt(6)" ::: "memory");
        else if (t + 1 < nt) asm volatile("s_waitcnt vmcnt(0)" ::: "memory");
        __builtin_amdgcn_s_barrier();
      }
    }
  }

  // ---- fused epilogue: RoPE (q/k) or plain (v), bf16 scatter ----
  const int n0 = (int)colBase;   // 128-aligned head window
  unsigned short* dst;
  int rstride, colofs;
  bool dorope;
  if (n0 < 4096)       { dst = qr;   rstride = NHQ * HDIM;  colofs = n0;        dorope = true; }
  else if (n0 < 5120)  { dst = kr;   rstride = NKVH * HDIM; colofs = n0 - 4096; dorope = true; }
  else                 { dst = vbuf; rstride = NKVH * HDIM; colofs = n0 - 5120; dorope = false; }
  const float c0 = -13.287712379549449f / 64.0f;  // -log2(10000)/64
  float fA[2], fB[2];
#pragma unroll
  for (int e = 0; e < 2; ++e) {
    int d = wn * 32 + e * 16 + m16;
    fA[e] = exp2f(c0 * (float)(d >> 1));
    fB[e] = exp2f(c0 * (float)((d >> 1) + 32));
  }
#pragma unroll
  for (int mf = 0; mf < 4; ++mf) {
#pragma unroll
    for (int reg = 0; reg < 4; ++reg) {
      int grow = (int)rowBase + wm * 64 + mf * 16 + quad * 4 + reg;
      unsigned short* drow = dst + (long)grow * rstride + colofs;
      if (dorope) {
        int p = pos[grow];
        p = p < 0 ? 0 : (p > SEQ - 1 ? SEQ - 1 : p);
        float pf = (float)p;
#pragma unroll
        for (int e = 0; e < 2; ++e) {
          int d = wn * 32 + e * 16 + m16;
          float lo = acc[mf][e][reg], hi = acc[mf][e + 2][reg];
          float s1, cc1, s2, cc2;
          __sincosf(pf * fA[e], &s1, &cc1);
          __sincosf(pf * fB[e], &s2, &cc2);
          drow[d]      = f2bf(lo * cc1 - hi * s1);
          drow[d + 64] = f2bf(hi * cc2 + lo * s2);
        }
      } else {
#pragma unroll
        for (int e = 0; e < 2; ++e) {
          int d = wn * 32 + e * 16 + m16;
          drow[d]      = f2bf(acc[mf][e][reg]);
          drow[d + 64] = f2bf(acc[mf][e + 2][reg]);
        }
      }
    }
  }
}

// ============== Output-proj GEMM: C[4096,4096] f32 = A @ B^T ===================
// Tile 256x256, BK=32, 8 waves (2M x 4N), per-wave 128x64 (m201 intensity).
// LDS rows packed 2-per-128B: logical (r,q) at p=r>>1, slot=(q+4(r&1))^(p&7).
// Frag read => slot=(quad+4(m16&1))^(m16>>1): 16 lanes cover 8 slots 2x (free).
// Ring-3 both, ONE barrier/tile, vmcnt(4) counted. Grid 16x16=256 (1 round).
__global__ __launch_bounds__(512, 2) void gemm_o(const unsigned short* __restrict__ A,
                                                 const unsigned short* __restrict__ B,
                                                 float* __restrict__ C) {
  const int K = 4096, N = 4096, nt = 128;
  __shared__ unsigned short AS[3][8192];   // 48 KB: [128 prow][64 sh] per slot
  __shared__ unsigned short BS[3][8192];   // 48 KB
  const int tid  = threadIdx.x;
  const int lane = tid & 63;
  const int wave = tid >> 6;
  const int m16  = lane & 15;
  const int quad = lane >> 4;
  const int wm   = wave >> 2;   // 0..1: rows wm*128..+127
  const int wn   = wave & 3;    // 0..3: cols wn*64..+63

  const int gx = 16;
  const int orig = blockIdx.y * gx + blockIdx.x;
  const int swz = (orig & 7) * 32 + (orig >> 3);
  const long rowBase = (long)(swz / gx) * 256;
  const long colBase = (long)(swz % gx) * 256;

  // frag read offsets (shorts): p&7 == m16>>1 for all mf/nf
  const int slot8 = ((quad + 4 * (m16 & 1)) ^ (m16 >> 1)) * 8;
  const int aob = (wm * 64 + (m16 >> 1)) * 64 + slot8;   // + mf*512
  const int bob = (wn * 32 + (m16 >> 1)) * 64 + slot8;   // + nf*512

  // staging source (inverse of packed swizzle)
  const long Kl = K;
  const int z = (tid & 7) ^ ((tid >> 3) & 7);
  const long srow = 2 * (tid >> 3) + (z >> 2);
  const int sk = (z & 3) * 8;
  const unsigned short* oA = A + (rowBase + srow) * Kl + sk;
  const unsigned short* oB = B + (colBase + srow) * Kl + sk;
  const int dofs = wave * 512;

#define OSTG_A(sl_, ko_) { GLOAD_LDS16(oA + (ko_),            &AS[sl_][dofs]);         \
                           GLOAD_LDS16(oA + (ko_) + 128 * Kl, &AS[sl_][4096 + dofs]); }
#define OSTG_B(sl_, ko_) { GLOAD_LDS16(oB + (ko_),            &BS[sl_][dofs]);         \
                           GLOAD_LDS16(oB + (ko_) + 128 * Kl, &BS[sl_][4096 + dofs]); }

  f32x4 acc[8][4] = {};   // [mf][nf]

  OSTG_A(0, 0);  OSTG_B(0, 0);
  OSTG_A(1, 32); OSTG_B(1, 32);
  asm volatile("s_waitcnt vmcnt(4)" ::: "memory");
  __builtin_amdgcn_s_barrier();

  for (int g = 0; g < 43; ++g) {
#pragma unroll
    for (int u = 0; u < 3; ++u) {
      const int t = g * 3 + u;
      if (t < nt) {
        const bool doStage = (t + 2) < nt;
        const long kn = (long)(t + 2) * 32;
        bf16x8 af[8], bfr[4];
#pragma unroll
        for (int nf = 0; nf < 4; ++nf)
          bfr[nf] = *(const bf16x8*)(&BS[u][bob + nf * 512]);
#pragma unroll
        for (int mf = 0; mf < 4; ++mf)
          af[mf] = *(const bf16x8*)(&AS[u][aob + mf * 512]);
        if (doStage) { OSTG_A((u + 2) % 3, kn); OSTG_B((u + 2) % 3, kn); }
#pragma unroll
        for (int mf = 4; mf < 8; ++mf)
          af[mf] = *(const bf16x8*)(&AS[u][aob + mf * 512]);
        __builtin_amdgcn_s_setprio(1);
#pragma unroll
        for (int mf = 0; mf < 4; ++mf)
#pragma unroll
          for (int nf = 0; nf < 4; ++nf)
            acc[mf][nf] = __builtin_amdgcn_mfma_f32_16x16x32_bf16(af[mf], bfr[nf], acc[mf][nf], 0, 0, 0);
#pragma unroll
        for (int mf = 4; mf < 8; ++mf)
#pragma unroll
          for (int nf = 0; nf < 4; ++nf)
            acc[mf][nf] = __builtin_amdgcn_mfma_f32_16x16x32_bf16(af[mf], bfr[nf], acc[mf][nf], 0, 0, 0);
        __builtin_amdgcn_s_setprio(0);
        if (doStage)         asm volatile("s_waitcnt vmcnt(4)" ::: "memory");
        else if (t + 1 < nt) asm volatile("s_waitcnt vmcnt(0)" ::: "memory");
        __builtin_amdgcn_s_barrier();
      }
    }
  }

#pragma unroll
  for (int mf = 0; mf < 8; ++mf)
#pragma unroll
    for (int nf = 0; nf < 4; ++nf) {
      long c = colBase + wn * 64 + nf * 16 + m16;
#pragma unroll
      for (int reg = 0; reg < 4; ++reg) {
        long row = rowBase + wm * 128 + mf * 16 + quad * 4 + reg;
        C[row * N + c] = acc[mf][nf][reg];
      }
    }
}

// ---------------- Flash attention (causal, GQA), bf16 MFMA ----------------
// T14 async-STAGE: K/V double-buffered; issue kt+1's K gloads + V reg loads
// right after QK^T(kt); drain + scatter after PV(kt). One __syncthreads/tile.
#define ATT_SCALE_L2 0.12754227022f  // (1/sqrt(128)) * log2(e)
__global__ __launch_bounds__(256) void attn_k(const unsigned short* __restrict__ Qp,
                                              const unsigned short* __restrict__ Kp,
                                              const unsigned short* __restrict__ Vp,
                                              unsigned short* __restrict__ Op) {
  const int pr = blockIdx.x, h = blockIdx.y, b = blockIdx.z;
  const int kvh = h >> 2;
  const int tid = threadIdx.x, wave = tid >> 6, lane = tid & 63;
  const int m16 = lane & 15, quad = lane >> 4;

  __shared__ unsigned short Ks[2][64][128];   // dbuf [key][d], xor swizzle
  __shared__ unsigned short Vt[2][128][64];   // dbuf [d][key], additive rotation
  __shared__ unsigned short Ps[4][32][64];    // per-wave P

  const unsigned short* Kh = Kp + (long)(b * SEQ) * (NKVH * HDIM) + kvh * HDIM;
  const unsigned short* Vh = Vp + (long)(b * SEQ) * (NKVH * HDIM) + kvh * HDIM;

#define STAGE_K(ktv, bufp) {                                               \
    _Pragma("unroll")                                                      \
    for (int it_ = 0; it_ < 4; ++it_) {                                    \
      int c_ = it_ * 256 + tid;                                            \
      int row_ = c_ >> 4, psg_ = c_ & 15;                                  \
      int sg_ = (psg_ & 8) | ((psg_ & 7) ^ (row_ & 7));                    \
      GLOAD_LDS16(Kh + ((long)(ktv) * 64 + row_) * (NKVH * HDIM) + sg_ * 8,\
                  ((unsigned short*)(bufp)) + (it_ * 256 + wave * 64) * 8);\
    } }

#define LOAD_V(ktv, dvv) {                                                 \
    _Pragma("unroll")                                                      \
    for (int it_ = 0; it_ < 4; ++it_)                                      \
      dvv[it_] = *(const uint4*)(Vh + ((long)(ktv) * 64 + lane) * (NKVH * HDIM) + (it_ * 4 + wave) * 8); }

#define SCATTER_V(bufp, dvv) {                                             \
    _Pragma("unroll")                                                      \
    for (int it_ = 0; it_ < 4; ++it_) {                                    \
      const unsigned short* pv_ = (const unsigned short*)&dvv[it_];        \
      int seg_ = it_ * 4 + wave;                                           \
      _Pragma("unroll")                                                    \
      for (int e_ = 0; e_ < 8; ++e_) {                                     \
        int d_ = seg_ * 8 + e_;                                            \
        (bufp)[d_][((((lane >> 3) + d_) & 7) * 8) + (lane & 7)] = pv_[e_]; \
      } } }

  for (int pass = 0; pass < 2; ++pass) {
    const int qt = pass ? pr : (7 - pr);
    const int qbase = qt * 128;
    const int wq_lo = qbase + wave * 32;

    bf16x8 qa[2][4];
#pragma unroll
    for (int i = 0; i < 2; ++i) {
      const unsigned short* qrow =
          Qp + (long)(b * SEQ + wq_lo + i * 16 + m16) * (NHQ * HDIM) + h * HDIM;
#pragma unroll
      for (int kk = 0; kk < 4; ++kk)
        qa[i][kk] = *(const bf16x8*)(qrow + kk * 32 + quad * 8);
    }

    f32x4 o[2][8] = {};
    float mrow[2][4], lrow[2][4];
#pragma unroll
    for (int i = 0; i < 2; ++i)
#pragma unroll
      for (int r = 0; r < 4; ++r) { mrow[i][r] = -1e30f; lrow[i][r] = 0.f; }

    const int nkt = qt * 2 + 2;

    {  // prologue: stage kt=0 into buffer 0
      STAGE_K(0, Ks[0]);
      uint4 dv[4];
      LOAD_V(0, dv);
      asm volatile("s_waitcnt vmcnt(0)" ::: "memory");
      SCATTER_V(Vt[0], dv);
    }
    __syncthreads();

    for (int kt = 0; kt < nkt; ++kt) {
      const int cb = kt & 1;
      const bool active = (kt * 64) <= (wq_lo + 31);
      const bool more = (kt + 1) < nkt;

      f32x4 s4[2][4] = {};
      if (active) {
        __builtin_amdgcn_s_setprio(1);
#pragma unroll
        for (int kk = 0; kk < 4; ++kk) {
          bf16x8 kbf[4];
#pragma unroll
          for (int j = 0; j < 4; ++j) {
            int row = j * 16 + m16;
            int cl = kk * 4 + quad;
            int ps = (cl & 8) | ((cl & 7) ^ (row & 7));
            kbf[j] = *(const bf16x8*)(&Ks[cb][row][ps * 8]);
          }
#pragma unroll
          for (int i = 0; i < 2; ++i)
#pragma unroll
            for (int j = 0; j < 4; ++j)
              s4[i][j] = __builtin_amdgcn_mfma_f32_16x16x32_bf16(qa[i][kk], kbf[j], s4[i][j], 0, 0, 0);
        }
        __builtin_amdgcn_s_setprio(0);
      }

      // ---- T14: issue next tile's loads early; HBM latency hides under softmax+PV
      uint4 dv[4];
      if (more) {
        STAGE_K(kt + 1, Ks[cb ^ 1]);
        LOAD_V(kt + 1, dv);
      }
      asm volatile("" ::: "memory");

      if (active) {
        const bool full = (kt * 64 + 63) <= wq_lo;
#pragma unroll
        for (int i = 0; i < 2; ++i) {
#pragma unroll
          for (int r = 0; r < 4; ++r) {
            const int qrow = i * 16 + quad * 4 + r;
            const int qi = qbase + wave * 32 + qrow;
            float v[4];
#pragma unroll
            for (int j = 0; j < 4; ++j) {
              v[j] = s4[i][j][r] * ATT_SCALE_L2;
              if (!full && (kt * 64 + j * 16 + m16 > qi)) v[j] = -1e30f;
            }
            float mx = fmaxf(fmaxf(v[0], v[1]), fmaxf(v[2], v[3]));
            mx = fmaxf(mx, __shfl_xor(mx, 1));
            mx = fmaxf(mx, __shfl_xor(mx, 2));
            mx = fmaxf(mx, __shfl_xor(mx, 4));
            mx = fmaxf(mx, __shfl_xor(mx, 8));
            float mold = mrow[i][r];
            float mnew = fmaxf(mold, mx);
            float alpha = exp2f(mold - mnew);
            float rs = 0.f;
#pragma unroll
            for (int j = 0; j < 4; ++j) {
              float pj = exp2f(v[j] - mnew);
              rs += pj;
              int col = j * 16 + m16;
              Ps[wave][qrow][((((col >> 3) + qrow) & 7) * 8) + (col & 7)] = f2bf(pj);
            }
            rs += __shfl_xor(rs, 1); rs += __shfl_xor(rs, 2);
            rs += __shfl_xor(rs, 4); rs += __shfl_xor(rs, 8);
            lrow[i][r] = lrow[i][r] * alpha + rs;
            mrow[i][r] = mnew;
#pragma unroll
            for (int n = 0; n < 8; ++n) o[i][n][r] *= alpha;
          }
        }
        __builtin_amdgcn_s_setprio(1);
#pragma unroll
        for (int kk = 0; kk < 2; ++kk) {
          bf16x8 pa[2], vb[8];
#pragma unroll
          for (int i = 0; i < 2; ++i) {
            int row = i * 16 + m16;
            pa[i] = *(const bf16x8*)(&Ps[wave][row][(((kk * 4 + quad) + row) & 7) * 8]);
          }
#pragma unroll
          for (int n = 0; n < 8; ++n) {
            int row = n * 16 + m16;
            vb[n] = *(const bf16x8*)(&Vt[cb][row][(((kk * 4 + quad) + row) & 7) * 8]);
          }
#pragma unroll
          for (int i = 0; i < 2; ++i)
#pragma unroll
            for (int n = 0; n < 8; ++n)
              o[i][n] = __builtin_amdgcn_mfma_f32_16x16x32_bf16(pa[i], vb[n], o[i][n], 0, 0, 0);
        }
        __builtin_amdgcn_s_setprio(0);
      }

      if (more) {
        asm volatile("s_waitcnt vmcnt(0)" ::: "memory");
        SCATTER_V(Vt[cb ^ 1], dv);
      }
      __syncthreads();
    }

#pragma unroll
    for (int i = 0; i < 2; ++i) {
#pragma unroll
      for (int r = 0; r < 4; ++r) {
        float inv = 1.0f / lrow[i][r];
        unsigned short* orow =
            Op + (long)(b * SEQ + wq_lo + i * 16 + quad * 4 + r) * (NHQ * HDIM) + h * HDIM;
#pragma unroll
        for (int n = 0; n < 8; ++n)
          orow[n * 16 + m16] = f2bf(o[i][n][r] * inv);
      }
    }
  }
}

// ---------------- launch ----------------
extern "C" void kernel_launch(void* const* d_in, const int* in_sizes, int n_in,
                              void* d_out, int out_size, void* d_ws, size_t ws_size,
                              hipStream_t stream) {
  (void)in_sizes; (void)n_in; (void)out_size; (void)ws_size;
  const float* x  = (const float*)d_in[0];
  const int* pos  = (const int*)d_in[1];
  const float* wq = (const float*)d_in[3];
  const float* wk = (const float*)d_in[4];
  const float* wv = (const float*)d_in[5];
  const float* wo = (const float*)d_in[6];
  float* out = (float*)d_out;

  char* ws = (char*)d_ws;
  unsigned short* xb    = (unsigned short*)(ws);                   // 32MB bf16 x
  unsigned short* wqkv  = (unsigned short*)(ws + (32ll << 20));    // 48MB bf16 [wq;wk;wv]
  unsigned short* wob   = (unsigned short*)(ws + (80ll << 20));    // 32MB bf16 wo
  unsigned short* qr    = (unsigned short*)(ws + (112ll << 20));   // 32MB q roped bf16
  unsigned short* kr    = (unsigned short*)(ws + (144ll << 20));   // 8MB  k roped bf16
  unsigned short* vb_   = (unsigned short*)(ws + (152ll << 20));   // 8MB  v bf16
  unsigned short* ao    = (unsigned short*)(ws + (160ll << 20));   // 32MB attn out bf16

  cast_all_k<<<57344, 256, 0, stream>>>(x, wq, wk, wv, wo, xb, wqkv, wob);
  gemm_qkv<<<dim3(48, 16), 512, 0, stream>>>(xb, wqkv, pos, qr, kr, vb_);
  attn_k<<<dim3(4, 32, 4), 256, 0, stream>>>(qr, kr, vb_, ao);
  gemm_o<<<dim3(16, 16), 512, 0, stream>>>(ao, wob, out);
}